// Round 1
// baseline (991.846 us; speedup 1.0000x reference)
//
#include <hip/hip_runtime.h>
#include <stdint.h>

#define NB 32
#define NN 524288
#define PP (NN / 2)
#define NPTS 16384
#define CAP 32768          // candidate buffer per batch (E[M]=22.9k, sd=147)
#define SCAP 20480         // scatter buffer per batch (<=16384+maxbin)
#define NBINS 4096
#define THRESH 0.0625f     // 1/16: 16384th smallest u ~= 0.0447 << 1/16
#define PARTITIONABLE 1    // JAX >= 0.4.36 default; flip to 0 if absmax != 0

struct Keys { uint32_t k[2 * NB]; };

__host__ __device__ static inline void tf2x32(uint32_t k0, uint32_t k1,
                                              uint32_t x0, uint32_t x1,
                                              uint32_t* o0, uint32_t* o1) {
  uint32_t ks2 = k0 ^ k1 ^ 0x1BD11BDAu;
  x0 += k0; x1 += k1;
#define TFR(r) { x0 += x1; x1 = (x1 << (r)) | (x1 >> (32 - (r))); x1 ^= x0; }
  TFR(13) TFR(15) TFR(26) TFR(6)
  x0 += k1; x1 += ks2 + 1u;
  TFR(17) TFR(29) TFR(16) TFR(24)
  x0 += ks2; x1 += k0 + 2u;
  TFR(13) TFR(15) TFR(26) TFR(6)
  x0 += k0; x1 += k1 + 3u;
  TFR(17) TFR(29) TFR(16) TFR(24)
  x0 += k1; x1 += ks2 + 4u;
  TFR(13) TFR(15) TFR(26) TFR(6)
  x0 += ks2; x1 += k0 + 5u;
#undef TFR
  *o0 = x0; *o1 = x1;
}

// K1: mask + threefry uniform + candidate append (u < 1/16 among valid).
__global__ __launch_bounds__(256) void k_candidates(
    const float* __restrict__ p, Keys keys,
    uint64_t* __restrict__ cand, uint32_t* __restrict__ cand_cnt) {
  const int b = blockIdx.y;
  const int i = blockIdx.x * 256 + threadIdx.x;
  const uint32_t kp0 = keys.k[2 * b], kp1 = keys.k[2 * b + 1];
  uint32_t o0, o1, bits;
#if PARTITIONABLE
  tf2x32(kp0, kp1, 0u, (uint32_t)i, &o0, &o1);
  bits = o0 ^ o1;
#else
  if (i < PP) { tf2x32(kp0, kp1, (uint32_t)i, (uint32_t)(PP + i), &o0, &o1); bits = o0; }
  else        { tf2x32(kp0, kp1, (uint32_t)(i - PP), (uint32_t)i, &o0, &o1); bits = o1; }
#endif
  float u = __uint_as_float((bits >> 9) | 0x3F800000u) - 1.0f;
  const float* pp = p + ((size_t)b * NN + (size_t)i) * 3;
  float s = (pp[0] + pp[1]) + pp[2];   // match XLA's sequential 3-elem reduce
  bool c = (s != 0.0f) && (u < THRESH);

  __shared__ uint32_t lcnt, lbase;
  if (threadIdx.x == 0) lcnt = 0u;
  __syncthreads();
  uint32_t loc = 0u;
  if (c) loc = atomicAdd(&lcnt, 1u);
  __syncthreads();
  if (threadIdx.x == 0) lbase = atomicAdd(&cand_cnt[b], lcnt);
  __syncthreads();
  if (c) {
    uint32_t slot = lbase + loc;
    if (slot < CAP)
      cand[(size_t)b * CAP + slot] =
          ((uint64_t)__float_as_uint(u) << 32) | (uint32_t)i;
  }
}

// K2: per-batch counting sort by value-linear bin (bin = u*65536, exact).
__global__ __launch_bounds__(1024) void k_countsort(
    const uint64_t* __restrict__ cand, const uint32_t* __restrict__ cand_cnt,
    uint64_t* __restrict__ sorted, uint32_t* __restrict__ gcum) {
  const int b = blockIdx.x;
  const int t = threadIdx.x;
  uint32_t M = cand_cnt[b]; if (M > CAP) M = CAP;

  __shared__ uint32_t hist[NBINS];
  __shared__ uint32_t cum[NBINS + 1];
  __shared__ uint32_t fill[NBINS];
  __shared__ uint32_t psum[1024];

  for (int j = t; j < NBINS; j += 1024) { hist[j] = 0u; fill[j] = 0u; }
  __syncthreads();

  const uint64_t* cb = cand + (size_t)b * CAP;
  for (uint32_t j = t; j < M; j += 1024) {
    float u = __uint_as_float((uint32_t)(cb[j] >> 32));
    atomicAdd(&hist[(int)(u * 65536.0f)], 1u);
  }
  __syncthreads();

  uint32_t h0 = hist[4 * t], h1 = hist[4 * t + 1],
           h2 = hist[4 * t + 2], h3 = hist[4 * t + 3];
  psum[t] = h0 + h1 + h2 + h3;
  __syncthreads();
  for (int off = 1; off < 1024; off <<= 1) {
    uint32_t add = (t >= off) ? psum[t - off] : 0u;
    __syncthreads();
    psum[t] += add;
    __syncthreads();
  }
  uint32_t ex = (t > 0) ? psum[t - 1] : 0u;
  cum[4 * t]     = ex;
  cum[4 * t + 1] = ex + h0;
  cum[4 * t + 2] = ex + h0 + h1;
  cum[4 * t + 3] = ex + h0 + h1 + h2;
  if (t == 1023) cum[NBINS] = psum[1023];
  __syncthreads();

  for (int j = t; j <= NBINS; j += 1024)
    gcum[(size_t)b * (NBINS + 1) + j] = cum[j];

  uint64_t* sb = sorted + (size_t)b * SCAP;
  for (uint32_t j = t; j < M; j += 1024) {
    uint64_t key = cb[j];
    float u = __uint_as_float((uint32_t)(key >> 32));
    int bin = (int)(u * 65536.0f);
    uint32_t c = cum[bin];
    if (c < NPTS) {                     // bins fully past rank 16384: drop
      uint32_t pos = atomicAdd(&fill[bin], 1u);
      uint32_t sl = c + pos;
      if (sl < SCAP) sb[sl] = key;
    }
  }
}

// K3: one thread per bin: selection-sort segment by full key, emit ranks<16384.
__global__ __launch_bounds__(256) void k_emit(
    const float* __restrict__ p, uint64_t* __restrict__ sorted,
    const uint32_t* __restrict__ gcum, float* __restrict__ out) {
  const int b = blockIdx.y;
  const int bin = blockIdx.x * 256 + threadIdx.x;
  const uint32_t* gc = gcum + (size_t)b * (NBINS + 1);
  uint32_t c0 = gc[bin];
  if (c0 >= NPTS) return;
  uint32_t c1 = gc[bin + 1];
  uint32_t cnt = c1 - c0;
  if (cnt > SCAP - c0) cnt = SCAP - c0;     // defensive (never in practice)
  uint32_t lim = NPTS - c0; if (cnt < lim) lim = cnt;

  uint64_t* seg = sorted + (size_t)b * SCAP + c0;
  const float* pb = p + (size_t)b * NN * 3;
  float* ob = out + (size_t)b * NPTS * 3;

  for (uint32_t j = 0; j < lim; ++j) {
    uint32_t mi = j;
    uint64_t mv = seg[j];
    for (uint32_t l = j + 1; l < cnt; ++l) {
      uint64_t v = seg[l];
      if (v < mv) { mv = v; mi = l; }
    }
    if (mi != j) { seg[mi] = seg[j]; seg[j] = mv; }
    uint32_t idx = (uint32_t)mv;
    size_t r = c0 + j;
    ob[3 * r]     = pb[3 * (size_t)idx];
    ob[3 * r + 1] = pb[3 * (size_t)idx + 1];
    ob[3 * r + 2] = pb[3 * (size_t)idx + 2];
  }
}

extern "C" void kernel_launch(void* const* d_in, const int* in_sizes, int n_in,
                              void* d_out, int out_size, void* d_ws, size_t ws_size,
                              hipStream_t stream) {
  const float* p = (const float*)d_in[0];
  float* out = (float*)d_out;
  uint8_t* ws = (uint8_t*)d_ws;

  size_t off_cand   = 0;
  size_t off_sorted = off_cand + (size_t)NB * CAP * 8;            // 8 MB
  size_t off_gcum   = off_sorted + (size_t)NB * SCAP * 8;         // +5.24 MB
  size_t off_cnt    = off_gcum + (size_t)NB * (NBINS + 1) * 4;    // +524 KB
  uint64_t* cand     = (uint64_t*)(ws + off_cand);
  uint64_t* sorted   = (uint64_t*)(ws + off_sorted);
  uint32_t* gcum     = (uint32_t*)(ws + off_gcum);
  uint32_t* cand_cnt = (uint32_t*)(ws + off_cnt);

  // Host-side threefry key derivation: key(42) -> split(32) -> split(2)[0].
  Keys keys;
#if PARTITIONABLE
  for (int b = 0; b < NB; ++b) {
    uint32_t kb0, kb1, kp0, kp1;
    tf2x32(0u, 42u, 0u, (uint32_t)b, &kb0, &kb1);   // fold-like split
    tf2x32(kb0, kb1, 0u, 0u, &kp0, &kp1);           // kperm = row 0
    keys.k[2 * b] = kp0; keys.k[2 * b + 1] = kp1;
  }
#else
  uint32_t o64[64];
  for (int i = 0; i < 32; ++i) {
    uint32_t a, c;
    tf2x32(0u, 42u, (uint32_t)i, (uint32_t)(32 + i), &a, &c);
    o64[i] = a; o64[32 + i] = c;
  }
  for (int b = 0; b < NB; ++b) {
    uint32_t kb0 = o64[2 * b], kb1 = o64[2 * b + 1];
    uint32_t a0, a1, b0, b1;
    tf2x32(kb0, kb1, 0u, 2u, &a0, &a1);
    tf2x32(kb0, kb1, 1u, 3u, &b0, &b1);
    keys.k[2 * b] = a0; keys.k[2 * b + 1] = b0;     // kperm = (y0[0], y0[1])
  }
#endif

  hipMemsetAsync(cand_cnt, 0, NB * sizeof(uint32_t), stream);
  dim3 g1(NN / 256, NB);
  k_candidates<<<g1, 256, 0, stream>>>(p, keys, cand, cand_cnt);
  k_countsort<<<NB, 1024, 0, stream>>>(cand, cand_cnt, sorted, gcum);
  dim3 g3(NBINS / 256, NB);
  k_emit<<<g3, 256, 0, stream>>>(p, sorted, gcum, out);
}

// Round 2
// 331.345 us; speedup vs baseline: 2.9934x; 2.9934x over previous
//
#include <hip/hip_runtime.h>
#include <stdint.h>

#define NB 32
#define NN 524288
#define NPTS 16384
#define NSEG 8             // sub-counters per batch (kills atomic line contention)
#define SEGCAP 4096        // slots per segment (E=2870, sd~52)
#define SCAP 20480         // scatter buffer per batch (<=16384+maxbin)
#define NBINS 4096
#define THRESH 0.0625f     // 1/16: 16384th smallest u ~= 0.0447 << 1/16
#define CNTSTRIDE 32       // uint32s per counter -> 128B line padding

struct Keys { uint32_t k[2 * NB]; };

__host__ __device__ static inline void tf2x32(uint32_t k0, uint32_t k1,
                                              uint32_t x0, uint32_t x1,
                                              uint32_t* o0, uint32_t* o1) {
  uint32_t ks2 = k0 ^ k1 ^ 0x1BD11BDAu;
  x0 += k0; x1 += k1;
#define TFR(r) { x0 += x1; x1 = (x1 << (r)) | (x1 >> (32 - (r))); x1 ^= x0; }
  TFR(13) TFR(15) TFR(26) TFR(6)
  x0 += k1; x1 += ks2 + 1u;
  TFR(17) TFR(29) TFR(16) TFR(24)
  x0 += ks2; x1 += k0 + 2u;
  TFR(13) TFR(15) TFR(26) TFR(6)
  x0 += k0; x1 += k1 + 3u;
  TFR(17) TFR(29) TFR(16) TFR(24)
  x0 += k1; x1 += ks2 + 4u;
  TFR(13) TFR(15) TFR(26) TFR(6)
  x0 += ks2; x1 += k0 + 5u;
#undef TFR
  *o0 = x0; *o1 = x1;
}

// K1: 4 points/thread, float4 loads, per-block LDS compaction, one padded
// sub-counter atomic per block (no contended-line serialization).
__global__ __launch_bounds__(256) void k_candidates(
    const float* __restrict__ p, Keys keys,
    uint64_t* __restrict__ cand, uint32_t* __restrict__ cand_cnt) {
  const int b = blockIdx.y;
  const int t = threadIdx.x;
  const int i0 = (blockIdx.x * 256 + t) * 4;            // first of 4 points
  const uint32_t kp0 = keys.k[2 * b], kp1 = keys.k[2 * b + 1];

  // three coalesced float4 loads = this thread's 4 points (12 floats)
  const float4* p4 = (const float4*)(p + (size_t)b * NN * 3) +
                     (size_t)(blockIdx.x * 256) * 3 + (size_t)t * 3;
  float4 v0 = p4[0], v1 = p4[1], v2 = p4[2];
  float px[4], py[4], pz[4];
  px[0] = v0.x; py[0] = v0.y; pz[0] = v0.z;
  px[1] = v0.w; py[1] = v1.x; pz[1] = v1.y;
  px[2] = v1.z; py[2] = v1.w; pz[2] = v2.x;
  px[3] = v2.y; py[3] = v2.z; pz[3] = v2.w;

  uint64_t mykeys[4];
  int nc = 0;
#pragma unroll
  for (int j = 0; j < 4; ++j) {
    uint32_t o0, o1;
    tf2x32(kp0, kp1, 0u, (uint32_t)(i0 + j), &o0, &o1);
    uint32_t bits = o0 ^ o1;
    float u = __uint_as_float((bits >> 9) | 0x3F800000u) - 1.0f;
    float s = (px[j] + py[j]) + pz[j];
    if ((s != 0.0f) && (u < THRESH))
      mykeys[nc++] = ((uint64_t)(bits >> 9) + 0x3F800000ull) << 32  // placeholder
                     ;  // overwritten below (keep compiler happy)
    if ((s != 0.0f) && (u < THRESH))
      mykeys[nc - 1] = ((uint64_t)__float_as_uint(u) << 32) | (uint32_t)(i0 + j);
  }

  __shared__ uint32_t lcnt, lbase;
  if (t == 0) lcnt = 0u;
  __syncthreads();
  uint32_t loc = 0u;
  if (nc) loc = atomicAdd(&lcnt, (uint32_t)nc);
  __syncthreads();
  const int seg = blockIdx.x & (NSEG - 1);
  if (t == 0)
    lbase = atomicAdd(&cand_cnt[(b * NSEG + seg) * CNTSTRIDE], lcnt);
  __syncthreads();
  uint64_t* cb = cand + ((size_t)b * NSEG + seg) * SEGCAP;
  for (int j = 0; j < nc; ++j) {
    uint32_t slot = lbase + loc + j;
    if (slot < SEGCAP) cb[slot] = mykeys[j];
  }
}

// K2: per-batch counting sort by value-linear bin (bin = u*65536, exact).
__global__ __launch_bounds__(1024) void k_countsort(
    const uint64_t* __restrict__ cand, const uint32_t* __restrict__ cand_cnt,
    uint64_t* __restrict__ sorted, uint32_t* __restrict__ gcum) {
  const int b = blockIdx.x;
  const int t = threadIdx.x;

  __shared__ uint32_t hist[NBINS];
  __shared__ uint32_t cum[NBINS + 1];
  __shared__ uint32_t fill[NBINS];
  __shared__ uint32_t psum[1024];
  __shared__ uint32_t mseg[NSEG];

  for (int j = t; j < NBINS; j += 1024) { hist[j] = 0u; fill[j] = 0u; }
  if (t < NSEG) {
    uint32_t m = cand_cnt[(b * NSEG + t) * CNTSTRIDE];
    mseg[t] = (m > SEGCAP) ? SEGCAP : m;
  }
  __syncthreads();

  const uint64_t* cb = cand + (size_t)b * NSEG * SEGCAP;
  for (int s = 0; s < NSEG; ++s) {
    uint32_t M = mseg[s];
    for (uint32_t j = t; j < M; j += 1024) {
      float u = __uint_as_float((uint32_t)(cb[s * SEGCAP + j] >> 32));
      atomicAdd(&hist[(int)(u * 65536.0f)], 1u);
    }
  }
  __syncthreads();

  uint32_t h0 = hist[4 * t], h1 = hist[4 * t + 1],
           h2 = hist[4 * t + 2], h3 = hist[4 * t + 3];
  psum[t] = h0 + h1 + h2 + h3;
  __syncthreads();
  for (int off = 1; off < 1024; off <<= 1) {
    uint32_t add = (t >= off) ? psum[t - off] : 0u;
    __syncthreads();
    psum[t] += add;
    __syncthreads();
  }
  uint32_t ex = (t > 0) ? psum[t - 1] : 0u;
  cum[4 * t]     = ex;
  cum[4 * t + 1] = ex + h0;
  cum[4 * t + 2] = ex + h0 + h1;
  cum[4 * t + 3] = ex + h0 + h1 + h2;
  if (t == 1023) cum[NBINS] = psum[1023];
  __syncthreads();

  for (int j = t; j <= NBINS; j += 1024)
    gcum[(size_t)b * (NBINS + 1) + j] = cum[j];

  uint64_t* sb = sorted + (size_t)b * SCAP;
  for (int s = 0; s < NSEG; ++s) {
    uint32_t M = mseg[s];
    for (uint32_t j = t; j < M; j += 1024) {
      uint64_t key = cb[s * SEGCAP + j];
      float u = __uint_as_float((uint32_t)(key >> 32));
      int bin = (int)(u * 65536.0f);
      uint32_t c = cum[bin];
      if (c < NPTS) {                   // bins fully past rank 16384: drop
        uint32_t pos = atomicAdd(&fill[bin], 1u);
        uint32_t sl = c + pos;
        if (sl < SCAP) sb[sl] = key;
      }
    }
  }
}

// K3: one thread per bin: selection-sort segment by full key, emit ranks<16384.
__global__ __launch_bounds__(256) void k_emit(
    const float* __restrict__ p, uint64_t* __restrict__ sorted,
    const uint32_t* __restrict__ gcum, float* __restrict__ out) {
  const int b = blockIdx.y;
  const int bin = blockIdx.x * 256 + threadIdx.x;
  const uint32_t* gc = gcum + (size_t)b * (NBINS + 1);
  uint32_t c0 = gc[bin];
  if (c0 >= NPTS) return;
  uint32_t c1 = gc[bin + 1];
  uint32_t cnt = c1 - c0;
  if (cnt > SCAP - c0) cnt = SCAP - c0;     // defensive (never in practice)
  uint32_t lim = NPTS - c0; if (cnt < lim) lim = cnt;

  uint64_t* seg = sorted + (size_t)b * SCAP + c0;
  const float* pb = p + (size_t)b * NN * 3;
  float* ob = out + (size_t)b * NPTS * 3;

  for (uint32_t j = 0; j < lim; ++j) {
    uint32_t mi = j;
    uint64_t mv = seg[j];
    for (uint32_t l = j + 1; l < cnt; ++l) {
      uint64_t v = seg[l];
      if (v < mv) { mv = v; mi = l; }
    }
    if (mi != j) { seg[mi] = seg[j]; seg[j] = mv; }
    uint32_t idx = (uint32_t)mv;
    size_t r = c0 + j;
    ob[3 * r]     = pb[3 * (size_t)idx];
    ob[3 * r + 1] = pb[3 * (size_t)idx + 1];
    ob[3 * r + 2] = pb[3 * (size_t)idx + 2];
  }
}

extern "C" void kernel_launch(void* const* d_in, const int* in_sizes, int n_in,
                              void* d_out, int out_size, void* d_ws, size_t ws_size,
                              hipStream_t stream) {
  const float* p = (const float*)d_in[0];
  float* out = (float*)d_out;
  uint8_t* ws = (uint8_t*)d_ws;

  size_t off_cand   = 0;                                          // 8 MB
  size_t off_sorted = off_cand + (size_t)NB * NSEG * SEGCAP * 8;  // +5.24 MB
  size_t off_gcum   = off_sorted + (size_t)NB * SCAP * 8;         // +0.52 MB
  size_t off_cnt    = off_gcum + (size_t)NB * (NBINS + 1) * 4;    // +32 KB
  uint64_t* cand     = (uint64_t*)(ws + off_cand);
  uint64_t* sorted   = (uint64_t*)(ws + off_sorted);
  uint32_t* gcum     = (uint32_t*)(ws + off_gcum);
  uint32_t* cand_cnt = (uint32_t*)(ws + off_cnt);

  // Host-side threefry key derivation (partitionable mode, verified absmax=0):
  // key(42) -> split(32) via cipher(key,(0,b)) -> split(2)[0] via cipher(kb,(0,0)).
  Keys keys;
  for (int b = 0; b < NB; ++b) {
    uint32_t kb0, kb1, kp0, kp1;
    tf2x32(0u, 42u, 0u, (uint32_t)b, &kb0, &kb1);
    tf2x32(kb0, kb1, 0u, 0u, &kp0, &kp1);
    keys.k[2 * b] = kp0; keys.k[2 * b + 1] = kp1;
  }

  hipMemsetAsync(cand_cnt, 0, NB * NSEG * CNTSTRIDE * sizeof(uint32_t), stream);
  dim3 g1(NN / 1024, NB);          // 4 points per thread
  k_candidates<<<g1, 256, 0, stream>>>(p, keys, cand, cand_cnt);
  k_countsort<<<NB, 1024, 0, stream>>>(cand, cand_cnt, sorted, gcum);
  dim3 g3(NBINS / 256, NB);
  k_emit<<<g3, 256, 0, stream>>>(p, sorted, gcum, out);
}

// Round 3
// 322.702 us; speedup vs baseline: 3.0736x; 1.0268x over previous
//
#include <hip/hip_runtime.h>
#include <stdint.h>

#define NB 32
#define NN 524288
#define NPTS 16384
#define NSEG 8             // padded sub-counters per batch for K1 block appends
#define SEGCAP 4096        // slots per segment (E=2870, sd~52)
#define SCAP 20480         // scatter buffer per batch (>= 16384 + max bin ~25)
#define NBINS 4096
#define THRESH 0.0625f     // 1/16: 16384th smallest u ~= 0.0447 << 1/16
#define CNTSTRIDE 32       // uint32s per counter -> 128B line padding

struct Keys { uint32_t k[2 * NB]; };

__host__ __device__ static inline void tf2x32(uint32_t k0, uint32_t k1,
                                              uint32_t x0, uint32_t x1,
                                              uint32_t* o0, uint32_t* o1) {
  uint32_t ks2 = k0 ^ k1 ^ 0x1BD11BDAu;
  x0 += k0; x1 += k1;
#define TFR(r) { x0 += x1; x1 = (x1 << (r)) | (x1 >> (32 - (r))); x1 ^= x0; }
  TFR(13) TFR(15) TFR(26) TFR(6)
  x0 += k1; x1 += ks2 + 1u;
  TFR(17) TFR(29) TFR(16) TFR(24)
  x0 += ks2; x1 += k0 + 2u;
  TFR(13) TFR(15) TFR(26) TFR(6)
  x0 += k0; x1 += k1 + 3u;
  TFR(17) TFR(29) TFR(16) TFR(24)
  x0 += k1; x1 += ks2 + 4u;
  TFR(13) TFR(15) TFR(26) TFR(6)
  x0 += ks2; x1 += k0 + 5u;
#undef TFR
  *o0 = x0; *o1 = x1;
}

// K1: mask + threefry + candidate append + fused per-batch histogram.
__global__ __launch_bounds__(256) void k_candidates(
    const float* __restrict__ p, Keys keys,
    uint64_t* __restrict__ cand, uint32_t* __restrict__ cand_cnt,
    uint32_t* __restrict__ hist) {
  const int b = blockIdx.y;
  const int t = threadIdx.x;
  const int i0 = (blockIdx.x * 256 + t) * 4;            // first of 4 points
  const uint32_t kp0 = keys.k[2 * b], kp1 = keys.k[2 * b + 1];

  const float4* p4 = (const float4*)(p + (size_t)b * NN * 3) +
                     (size_t)(blockIdx.x * 256) * 3 + (size_t)t * 3;
  float4 v0 = p4[0], v1 = p4[1], v2 = p4[2];
  float px[4] = {v0.x, v0.w, v1.z, v2.y};
  float py[4] = {v0.y, v1.x, v1.w, v2.z};
  float pz[4] = {v0.z, v1.y, v2.x, v2.w};

  uint32_t* hb = hist + (size_t)b * NBINS;
  uint64_t mykeys[4];
  int nc = 0;
#pragma unroll
  for (int j = 0; j < 4; ++j) {
    uint32_t o0, o1;
    tf2x32(kp0, kp1, 0u, (uint32_t)(i0 + j), &o0, &o1);
    uint32_t bits = o0 ^ o1;
    float u = __uint_as_float((bits >> 9) | 0x3F800000u) - 1.0f;
    float s = (px[j] + py[j]) + pz[j];
    if ((s != 0.0f) && (u < THRESH)) {
      mykeys[nc++] = ((uint64_t)__float_as_uint(u) << 32) | (uint32_t)(i0 + j);
      atomicAdd(&hb[(int)(u * 65536.0f)], 1u);
    }
  }

  __shared__ uint32_t lcnt, lbase;
  if (t == 0) lcnt = 0u;
  __syncthreads();
  uint32_t loc = 0u;
  if (nc) loc = atomicAdd(&lcnt, (uint32_t)nc);
  __syncthreads();
  const int seg = blockIdx.x & (NSEG - 1);
  if (t == 0)
    lbase = atomicAdd(&cand_cnt[(b * NSEG + seg) * CNTSTRIDE], lcnt);
  __syncthreads();
  uint64_t* cb = cand + ((size_t)b * NSEG + seg) * SEGCAP;
  for (int j = 0; j < nc; ++j) {
    uint32_t slot = lbase + loc + j;
    if (slot < SEGCAP) cb[slot] = mykeys[j];
  }
}

// K2: per-batch exclusive scan of the 4096-bin histogram + scatter count.
__global__ __launch_bounds__(1024) void k_scan(
    const uint32_t* __restrict__ hist, uint32_t* __restrict__ gcum,
    uint32_t* __restrict__ scount) {
  const int b = blockIdx.x;
  const int t = threadIdx.x;
  __shared__ uint32_t cum[NBINS + 1];
  __shared__ uint32_t psum[1024];

  const uint32_t* hb = hist + (size_t)b * NBINS;
  uint32_t h0 = hb[4 * t], h1 = hb[4 * t + 1],
           h2 = hb[4 * t + 2], h3 = hb[4 * t + 3];
  psum[t] = h0 + h1 + h2 + h3;
  __syncthreads();
  for (int off = 1; off < 1024; off <<= 1) {
    uint32_t add = (t >= off) ? psum[t - off] : 0u;
    __syncthreads();
    psum[t] += add;
    __syncthreads();
  }
  uint32_t ex = (t > 0) ? psum[t - 1] : 0u;
  cum[4 * t]     = ex;
  cum[4 * t + 1] = ex + h0;
  cum[4 * t + 2] = ex + h0 + h1;
  cum[4 * t + 3] = ex + h0 + h1 + h2;
  if (t == 1023) cum[NBINS] = psum[1023];
  __syncthreads();

  uint32_t* gc = gcum + (size_t)b * (NBINS + 1);
  for (int j = t; j <= NBINS; j += 1024) gc[j] = cum[j];

  // scount = cum[B*+1] where B* = last bin with cum[bin] < NPTS.
#pragma unroll
  for (int q = 0; q < 4; ++q) {
    int bin = 4 * t + q;
    if (cum[bin] < NPTS && cum[bin + 1] >= NPTS) {
      uint32_t sc = cum[bin + 1];
      if (sc > SCAP) sc = SCAP;
      scount[b] = sc;
    }
  }
  if (t == 1023 && cum[NBINS] < NPTS) scount[b] = cum[NBINS];  // defensive
}

// K3: thread-per-candidate scatter into bin-contiguous slots (unordered in bin).
__global__ __launch_bounds__(256) void k_scatter(
    const uint64_t* __restrict__ cand, const uint32_t* __restrict__ cand_cnt,
    const uint32_t* __restrict__ gcum, uint32_t* __restrict__ fill,
    uint64_t* __restrict__ sorted) {
  const int b = blockIdx.y;
  const int j = blockIdx.x * 256 + threadIdx.x;   // 0..NSEG*SEGCAP-1
  const int s = j >> 12;                           // j / SEGCAP
  const int jj = j & (SEGCAP - 1);
  uint32_t M = cand_cnt[(b * NSEG + s) * CNTSTRIDE];
  if (M > SEGCAP) M = SEGCAP;
  if ((uint32_t)jj >= M) return;
  uint64_t key = cand[((size_t)b * NSEG + s) * SEGCAP + jj];
  float u = __uint_as_float((uint32_t)(key >> 32));
  int bin = (int)(u * 65536.0f);
  uint32_t c0 = gcum[(size_t)b * (NBINS + 1) + bin];
  if (c0 >= NPTS) return;                          // bin fully past rank 16384
  uint32_t pos = atomicAdd(&fill[(size_t)b * NBINS + bin], 1u);
  uint32_t sl = c0 + pos;
  if (sl < SCAP) sorted[(size_t)b * SCAP + sl] = key;
}

// K4: thread-per-slot exact rank by counting smaller keys in own bin; emit.
__global__ __launch_bounds__(256) void k_rank(
    const float* __restrict__ p, const uint64_t* __restrict__ sorted,
    const uint32_t* __restrict__ gcum, const uint32_t* __restrict__ scount,
    float* __restrict__ out) {
  const int b = blockIdx.y;
  const uint32_t j = blockIdx.x * 256 + threadIdx.x;
  if (j >= scount[b]) return;
  const uint64_t* sb = sorted + (size_t)b * SCAP;
  uint64_t key = sb[j];
  float u = __uint_as_float((uint32_t)(key >> 32));
  int bin = (int)(u * 65536.0f);
  const uint32_t* gc = gcum + (size_t)b * (NBINS + 1);
  uint32_t c0 = gc[bin], c1 = gc[bin + 1];
  uint32_t r = c0;
  for (uint32_t l = c0; l < c1; ++l) r += (sb[l] < key) ? 1u : 0u;
  if (r < NPTS) {
    uint32_t idx = (uint32_t)key;
    const float* pp = p + (size_t)b * NN * 3 + 3 * (size_t)idx;
    float* ob = out + ((size_t)b * NPTS + r) * 3;
    ob[0] = pp[0]; ob[1] = pp[1]; ob[2] = pp[2];
  }
}

extern "C" void kernel_launch(void* const* d_in, const int* in_sizes, int n_in,
                              void* d_out, int out_size, void* d_ws, size_t ws_size,
                              hipStream_t stream) {
  const float* p = (const float*)d_in[0];
  float* out = (float*)d_out;
  uint8_t* ws = (uint8_t*)d_ws;

  size_t off_cand   = 0;                                            // 8 MB
  size_t off_sorted = off_cand + (size_t)NB * NSEG * SEGCAP * 8;    // +5.24 MB
  size_t off_gcum   = off_sorted + (size_t)NB * SCAP * 8;           // +0.52 MB
  size_t off_scnt   = off_gcum + (size_t)NB * (NBINS + 1) * 4;      // +128 B
  size_t off_zero   = off_scnt + 128;                               // zeroed region:
  size_t off_cnt    = off_zero;                                     //   cand_cnt 32 KB
  size_t off_hist   = off_cnt + (size_t)NB * NSEG * CNTSTRIDE * 4;  //   hist 512 KB
  size_t off_fill   = off_hist + (size_t)NB * NBINS * 4;            //   fill 512 KB
  size_t zero_bytes = off_fill + (size_t)NB * NBINS * 4 - off_zero;

  uint64_t* cand     = (uint64_t*)(ws + off_cand);
  uint64_t* sorted   = (uint64_t*)(ws + off_sorted);
  uint32_t* gcum     = (uint32_t*)(ws + off_gcum);
  uint32_t* scount   = (uint32_t*)(ws + off_scnt);
  uint32_t* cand_cnt = (uint32_t*)(ws + off_cnt);
  uint32_t* hist     = (uint32_t*)(ws + off_hist);
  uint32_t* fill     = (uint32_t*)(ws + off_fill);

  // Host-side threefry key derivation (partitionable mode, verified absmax=0):
  // key(42) -> split(32) via cipher(key,(0,b)) -> split(2)[0] via cipher(kb,(0,0)).
  Keys keys;
  for (int b = 0; b < NB; ++b) {
    uint32_t kb0, kb1, kp0, kp1;
    tf2x32(0u, 42u, 0u, (uint32_t)b, &kb0, &kb1);
    tf2x32(kb0, kb1, 0u, 0u, &kp0, &kp1);
    keys.k[2 * b] = kp0; keys.k[2 * b + 1] = kp1;
  }

  hipMemsetAsync(ws + off_zero, 0, zero_bytes, stream);
  dim3 g1(NN / 1024, NB);          // 4 points per thread
  k_candidates<<<g1, 256, 0, stream>>>(p, keys, cand, cand_cnt, hist);
  k_scan<<<NB, 1024, 0, stream>>>(hist, gcum, scount);
  dim3 g3(NSEG * SEGCAP / 256, NB);
  k_scatter<<<g3, 256, 0, stream>>>(cand, cand_cnt, gcum, fill, sorted);
  dim3 g4(SCAP / 256, NB);
  k_rank<<<g4, 256, 0, stream>>>(p, sorted, gcum, scount, out);
}